// Round 1
// baseline (187.044 us; speedup 1.0000x reference)
//
#include <hip/hip_runtime.h>
#include <stdint.h>

#define NN 100000
#define DEG 32
#define CC 128
#define BM 64   // rows (nodes) per block

typedef __attribute__((ext_vector_type(4))) float f32x4;
typedef __attribute__((ext_vector_type(4))) unsigned int u32x4;
typedef __attribute__((ext_vector_type(8))) short s16x8;

// fp32 -> bf16 bits, round-to-nearest-even
static __device__ __forceinline__ unsigned short f2b(float f) {
    unsigned u = __float_as_uint(f);
    u += 0x7fffu + ((u >> 16) & 1u);
    return (unsigned short)(u >> 16);
}
static __device__ __forceinline__ float b2f_lo(unsigned u) { return __uint_as_float(u << 16); }
static __device__ __forceinline__ float b2f_hi(unsigned u) { return __uint_as_float(u & 0xffff0000u); }

// x (fp32, N rows) -> xb (bf16, N+1 rows; row N = zeros for padding gathers)
__global__ __launch_bounds__(256) void cvt_x(const float* __restrict__ x,
                                             unsigned short* __restrict__ xb) {
    int i = blockIdx.x * blockDim.x + threadIdx.x;
    const int total = (NN + 1) * CC / 4;
    const int nx = NN * CC / 4;
    for (; i < total; i += gridDim.x * blockDim.x) {
        ushort4 o;
        if (i < nx) {
            f32x4 v = ((const f32x4*)x)[i];
            o.x = f2b(v[0]); o.y = f2b(v[1]); o.z = f2b(v[2]); o.w = f2b(v[3]);
        } else {
            o.x = 0; o.y = 0; o.z = 0; o.w = 0;
        }
        ((ushort4*)xb)[i] = o;
    }
}

// W (fp32, 128x128) -> Wb (bf16)
__global__ __launch_bounds__(256) void cvt_w(const float* __restrict__ W,
                                             unsigned short* __restrict__ Wb) {
    int i = blockIdx.x * 256 + threadIdx.x;   // 4096 threads x 4 elements = 16384
    f32x4 v = ((const f32x4*)W)[i];
    ushort4 o;
    o.x = f2b(v[0]); o.y = f2b(v[1]); o.z = f2b(v[2]); o.w = f2b(v[3]);
    ((ushort4*)Wb)[i] = o;
}

// Fused gather-aggregate + bf16 MFMA linear.
// Block = 256 threads = 4 waves; wave w owns M-tile rows [base + 16w, base + 16w + 16).
// A-frag layout for mfma_f32_16x16x32_bf16: lane l holds A[l&15][(l>>4)*8 + i], i=0..7.
// Each lane aggregates exactly its fragment channels -> no LDS h-tile needed.
// D layout: D[(l>>4)*4 + j][l&15].
template <int XB>
__global__ __launch_bounds__(256) void gin_main(
    const float* __restrict__ x, const unsigned short* __restrict__ xb,
    const int* __restrict__ ei, const float* __restrict__ eps_p,
    const float* __restrict__ W, const unsigned short* __restrict__ Wb,
    const float* __restrict__ bias, float* __restrict__ out) {
    __shared__ int sidx[DEG][BM + 2];   // transposed [d][r], padded: conflict-free
    const int tid = threadIdx.x;
    const int base = blockIdx.x * BM;

    // stage edge indices, coalesced global read, transposed LDS write
    for (int q = tid; q < BM * DEG; q += 256) {
        int r = q >> 5, d = q & 31;
        int row = base + r;
        sidx[d][r] = (row < NN) ? ei[row * DEG + d] : NN;
    }
    __syncthreads();

    const int w = tid >> 6, l = tid & 63;
    const int lr = l & 15, lk = l >> 4;
    const int kb = lk * 8;                    // channel base within a 32-wide K tile
    const int rloc = w * 16 + lr;
    const int arow = base + rloc;             // row this lane aggregates (A operand)

    const float eps1 = 1.0f + eps_p[0];

    float hacc[4][8];                         // [k-tile][element]: channel kt*32 + kb + i
    {
        int sr = (arow < NN) ? arow : 0;      // clamp (invalid rows never stored)
        #pragma unroll
        for (int kt = 0; kt < 4; ++kt) {
            const f32x4* p = (const f32x4*)(x + (size_t)sr * CC + kt * 32 + kb);
            f32x4 a = p[0], b = p[1];
            #pragma unroll
            for (int j = 0; j < 4; ++j) {
                hacc[kt][j] = eps1 * a[j];
                hacc[kt][4 + j] = eps1 * b[j];
            }
        }
    }

    // gather-aggregate over 32 neighbors
    #pragma unroll 4
    for (int d = 0; d < DEG; ++d) {
        int id = sidx[d][rloc];
        if (XB) {
            // bf16 path: row NN is the zero padding row -> branchless
            const unsigned short* g = xb + (size_t)id * CC + kb;
            #pragma unroll
            for (int kt = 0; kt < 4; ++kt) {
                u32x4 v = *(const u32x4*)(g + kt * 32);
                #pragma unroll
                for (int j = 0; j < 4; ++j) {
                    hacc[kt][2 * j]     += b2f_lo(v[j]);
                    hacc[kt][2 * j + 1] += b2f_hi(v[j]);
                }
            }
        } else {
            if (id < NN) {
                const float* g = x + (size_t)id * CC + kb;
                #pragma unroll
                for (int kt = 0; kt < 4; ++kt) {
                    f32x4 a = *(const f32x4*)(g + kt * 32);
                    f32x4 b = *(const f32x4*)(g + kt * 32 + 4);
                    #pragma unroll
                    for (int j = 0; j < 4; ++j) {
                        hacc[kt][j] += a[j];
                        hacc[kt][4 + j] += b[j];
                    }
                }
            }
        }
    }

    // build A fragments (bf16)
    s16x8 afrag[4];
    #pragma unroll
    for (int kt = 0; kt < 4; ++kt)
        #pragma unroll
        for (int j = 0; j < 8; ++j) afrag[kt][j] = (short)f2b(hacc[kt][j]);

    // out[r][co] = sum_k h[r][k] * W[co][k]  -> B[k][co] = W[co][k]
    // B-frag: lane l element i = W[nt*16 + (l&15)][kt*32 + (l>>4)*8 + i] : 16B contiguous
    f32x4 acc[8];
    #pragma unroll
    for (int nt = 0; nt < 8; ++nt) acc[nt] = (f32x4){0.f, 0.f, 0.f, 0.f};

    #pragma unroll
    for (int nt = 0; nt < 8; ++nt) {
        #pragma unroll
        for (int kt = 0; kt < 4; ++kt) {
            s16x8 bfrag;
            if (XB) {
                u32x4 v = *(const u32x4*)(Wb + (nt * 16 + lr) * CC + kt * 32 + kb);
                bfrag = __builtin_bit_cast(s16x8, v);
            } else {
                const f32x4* p = (const f32x4*)(W + (nt * 16 + lr) * CC + kt * 32 + kb);
                f32x4 a = p[0], b = p[1];
                #pragma unroll
                for (int j = 0; j < 4; ++j) {
                    bfrag[j] = (short)f2b(a[j]);
                    bfrag[4 + j] = (short)f2b(b[j]);
                }
            }
            acc[nt] = __builtin_amdgcn_mfma_f32_16x16x32_bf16(afrag[kt], bfrag, acc[nt], 0, 0, 0);
        }
    }

    // store D + bias; lane l writes rows base + w*16 + lk*4 + j, col nt*16 + lr
    #pragma unroll
    for (int nt = 0; nt < 8; ++nt) {
        float bv = bias[nt * 16 + lr];
        #pragma unroll
        for (int j = 0; j < 4; ++j) {
            int orow = base + w * 16 + lk * 4 + j;
            if (orow < NN) out[(size_t)orow * CC + nt * 16 + lr] = acc[nt][j] + bv;
        }
    }
}

extern "C" void kernel_launch(void* const* d_in, const int* in_sizes, int n_in,
                              void* d_out, int out_size, void* d_ws, size_t ws_size,
                              hipStream_t stream) {
    const float* x = (const float*)d_in[0];
    const int* ei = (const int*)d_in[1];
    const float* eps = (const float*)d_in[2];
    const float* W = (const float*)d_in[3];
    const float* b = (const float*)d_in[4];
    float* out = (float*)d_out;

    const size_t xb_elems = (size_t)(NN + 1) * CC;
    const size_t need = (xb_elems + (size_t)CC * CC) * sizeof(unsigned short);
    const int grid = (NN + BM - 1) / BM;

    if (ws_size >= need) {
        unsigned short* xb = (unsigned short*)d_ws;
        unsigned short* Wb = xb + xb_elems;
        cvt_x<<<2048, 256, 0, stream>>>(x, xb);
        cvt_w<<<16, 256, 0, stream>>>(W, Wb);
        gin_main<1><<<grid, 256, 0, stream>>>(x, xb, ei, eps, W, Wb, b, out);
    } else {
        gin_main<0><<<grid, 256, 0, stream>>>(x, nullptr, ei, eps, W, nullptr, b, out);
    }
}

// Round 2
// 144.255 us; speedup vs baseline: 1.2966x; 1.2966x over previous
//
#include <hip/hip_runtime.h>
#include <stdint.h>

#define NN 100000
#define DEG 32
#define CC 128
#define SW 152   // LDS A-tile row stride in bf16: mult-of-8 (16B align for b128); 304B/16B=19 groups, 19%8=3 odd -> reads hit 8-cyc conflict floor

typedef __attribute__((ext_vector_type(4))) float f32x4;
typedef __attribute__((ext_vector_type(4))) unsigned int u32x4;
typedef __attribute__((ext_vector_type(8))) short s16x8;

// fp32 -> bf16 bits, round-to-nearest-even
static __device__ __forceinline__ unsigned short f2b(float f) {
    unsigned u = __float_as_uint(f);
    u += 0x7fffu + ((u >> 16) & 1u);
    return (unsigned short)(u >> 16);
}
static __device__ __forceinline__ float b2f_lo(unsigned u) { return __uint_as_float(u << 16); }
static __device__ __forceinline__ float b2f_hi(unsigned u) { return __uint_as_float(u & 0xffff0000u); }

// x (fp32, N rows) -> xb (bf16, N+1 rows; row N = zeros for padding gathers)
__global__ __launch_bounds__(256) void cvt_x(const float* __restrict__ x,
                                             unsigned short* __restrict__ xb) {
    int i = blockIdx.x * blockDim.x + threadIdx.x;
    const int total = (NN + 1) * CC / 4;
    const int nx = NN * CC / 4;
    for (; i < total; i += gridDim.x * blockDim.x) {
        ushort4 o;
        if (i < nx) {
            f32x4 v = ((const f32x4*)x)[i];
            o.x = f2b(v[0]); o.y = f2b(v[1]); o.z = f2b(v[2]); o.w = f2b(v[3]);
        } else {
            o.x = 0; o.y = 0; o.z = 0; o.w = 0;
        }
        ((ushort4*)xb)[i] = o;
    }
}

// W (fp32, 128x128) -> Wb (bf16)
__global__ __launch_bounds__(256) void cvt_w(const float* __restrict__ W,
                                             unsigned short* __restrict__ Wb) {
    int i = blockIdx.x * 256 + threadIdx.x;
    f32x4 v = ((const f32x4*)W)[i];
    ushort4 o;
    o.x = f2b(v[0]); o.y = f2b(v[1]); o.z = f2b(v[2]); o.w = f2b(v[3]);
    ((ushort4*)Wb)[i] = o;
}

// Fused gather-aggregate + bf16 MFMA linear, coalesced-row gather version.
// Block = 256 = 4 independent waves (no __syncthreads). Wave owns 16 output rows.
// Gather: lane l = (slot s = l>>4, chunk c = l&15). Instruction t reads row
// id[s + 4t], bytes [c*16, c*16+16) -> 4 rows x 2 full 128B lines per instr.
// Reduce over slots: shfl_xor 16,32. Self term folded in at weight (1+eps)/4.
// A-tile in LDS (per wave), then mfma_f32_16x16x32_bf16 vs Wb from global.
__global__ __launch_bounds__(256) void gin_main(
    const unsigned short* __restrict__ xb, const int* __restrict__ ei,
    const float* __restrict__ eps_p, const unsigned short* __restrict__ Wb,
    const float* __restrict__ bias, float* __restrict__ out) {
    __shared__ int sid[4][16 * 32];            // [wave][r*32 + s*8 + t], d = s + 4t
    __shared__ unsigned short sA[4][16 * SW];  // [wave][r][0..127 used of SW]

    const int tid = threadIdx.x;
    const int w = tid >> 6, l = tid & 63;
    const int s = l >> 4, c = l & 15;
    const int wbase = blockIdx.x * 64 + w * 16;

    // ---- stage this wave's 16 rows of neighbor ids, transposed to [r][s][t]
    {
        const int r = l >> 2;              // 4 lanes per row
        const int row = wbase + r;
        const int j0 = (l & 3) * 8;        // this lane's 8 consecutive d's
        int4 a, b;
        if (row < NN) {
            const int4* p = (const int4*)(ei + (size_t)row * DEG + j0);
            a = p[0]; b = p[1];
        } else {
            a.x = NN; a.y = NN; a.z = NN; a.w = NN; b = a;
        }
        int idv[8] = {a.x, a.y, a.z, a.w, b.x, b.y, b.z, b.w};
        int* dst = sid[w] + r * 32;
        #pragma unroll
        for (int k = 0; k < 8; ++k) {
            const int d = j0 + k;
            dst[(d & 3) * 8 + (d >> 2)] = idv[k];   // pos = s*8 + t
        }
    }
    // wave-private LDS; compiler orders via lgkmcnt. No barrier.

    const float es = (1.0f + eps_p[0]) * 0.25f;   // self weight per replica (x4 after reduce)

    u32x4 g[2][9];   // double-buffered in-flight loads: 8 gathers + 1 self

    auto stageA = [&](int r, int buf) {
        const int* idp = sid[w] + r * 32 + s * 8;
        int4 i0 = *(const int4*)idp;
        int4 i1 = *(const int4*)(idp + 4);
        const unsigned short* bx = xb + c * 8;
        g[buf][0] = *(const u32x4*)(bx + (size_t)i0.x * CC);
        g[buf][1] = *(const u32x4*)(bx + (size_t)i0.y * CC);
        g[buf][2] = *(const u32x4*)(bx + (size_t)i0.z * CC);
        g[buf][3] = *(const u32x4*)(bx + (size_t)i0.w * CC);
        g[buf][4] = *(const u32x4*)(bx + (size_t)i1.x * CC);
        g[buf][5] = *(const u32x4*)(bx + (size_t)i1.y * CC);
        g[buf][6] = *(const u32x4*)(bx + (size_t)i1.z * CC);
        g[buf][7] = *(const u32x4*)(bx + (size_t)i1.w * CC);
        const int row = wbase + r;
        const int srow = (row < NN) ? row : NN;      // row NN = zeros
        g[buf][8] = *(const u32x4*)(bx + (size_t)srow * CC);
    };

    auto stageB = [&](int r, int buf) {
        float acc[8];
        u32x4 v = g[buf][8];
        #pragma unroll
        for (int j = 0; j < 4; ++j) {
            acc[2 * j]     = es * b2f_lo(v[j]);
            acc[2 * j + 1] = es * b2f_hi(v[j]);
        }
        #pragma unroll
        for (int t = 0; t < 8; ++t) {
            v = g[buf][t];
            #pragma unroll
            for (int j = 0; j < 4; ++j) {
                acc[2 * j]     += b2f_lo(v[j]);
                acc[2 * j + 1] += b2f_hi(v[j]);
            }
        }
        // reduce across the 4 slots (lanes l, l^16, l^32, l^48 hold same chunk)
        #pragma unroll
        for (int j = 0; j < 8; ++j) {
            acc[j] += __shfl_xor(acc[j], 16);
            acc[j] += __shfl_xor(acc[j], 32);
        }
        if (s == 0) {
            s16x8 o;
            #pragma unroll
            for (int j = 0; j < 8; ++j) o[j] = (short)f2b(acc[j]);
            *(s16x8*)(sA[w] + r * SW + c * 8) = o;   // 16B aligned (SW mult of 8)
        }
    };

    stageA(0, 0);
    #pragma unroll
    for (int r = 0; r < 16; ++r) {          // fully unrolled: all g[] indices static
        if (r < 15) stageA(r + 1, (r + 1) & 1);
        stageB(r, r & 1);
    }

    // ---- A fragments from LDS: lane l holds A[c][s*8 + kt*32 + i]
    s16x8 afrag[4];
    #pragma unroll
    for (int kt = 0; kt < 4; ++kt)
        afrag[kt] = *(const s16x8*)(sA[w] + c * SW + kt * 32 + s * 8);

    // ---- MFMA vs W (B[k][co] = W[co][k]); B-frag: lane l elem i = W[nt*16+c][kt*32+s*8+i]
    f32x4 acc[8];
    #pragma unroll
    for (int nt = 0; nt < 8; ++nt) acc[nt] = (f32x4){0.f, 0.f, 0.f, 0.f};
    #pragma unroll
    for (int nt = 0; nt < 8; ++nt) {
        #pragma unroll
        for (int kt = 0; kt < 4; ++kt) {
            s16x8 bfrag = *(const s16x8*)(Wb + (size_t)(nt * 16 + c) * CC + kt * 32 + s * 8);
            acc[nt] = __builtin_amdgcn_mfma_f32_16x16x32_bf16(afrag[kt], bfrag, acc[nt], 0, 0, 0);
        }
    }

    // ---- store: D[s*4 + j][nt*16 + c]
    #pragma unroll
    for (int nt = 0; nt < 8; ++nt) {
        const float bv = bias[nt * 16 + c];
        #pragma unroll
        for (int j = 0; j < 4; ++j) {
            const int orow = wbase + s * 4 + j;
            if (orow < NN) out[(size_t)orow * CC + nt * 16 + c] = acc[nt][j] + bv;
        }
    }
}

// fallback (ws too small): round-1 proven f32 path
__global__ __launch_bounds__(256) void gin_f32(
    const float* __restrict__ x, const int* __restrict__ ei,
    const float* __restrict__ eps_p, const float* __restrict__ W,
    const float* __restrict__ bias, float* __restrict__ out) {
    __shared__ int sidx[DEG][64 + 2];
    const int tid = threadIdx.x;
    const int base = blockIdx.x * 64;
    for (int q = tid; q < 64 * DEG; q += 256) {
        int r = q >> 5, d = q & 31;
        int row = base + r;
        sidx[d][r] = (row < NN) ? ei[row * DEG + d] : NN;
    }
    __syncthreads();
    const int w = tid >> 6, l = tid & 63;
    const int lr = l & 15, lk = l >> 4;
    const int kb = lk * 8;
    const int rloc = w * 16 + lr;
    const int arow = base + rloc;
    const float eps1 = 1.0f + eps_p[0];
    float hacc[4][8];
    {
        int sr = (arow < NN) ? arow : 0;
        #pragma unroll
        for (int kt = 0; kt < 4; ++kt) {
            const f32x4* p = (const f32x4*)(x + (size_t)sr * CC + kt * 32 + kb);
            f32x4 a = p[0], b = p[1];
            #pragma unroll
            for (int j = 0; j < 4; ++j) { hacc[kt][j] = eps1 * a[j]; hacc[kt][4 + j] = eps1 * b[j]; }
        }
    }
    #pragma unroll 4
    for (int d = 0; d < DEG; ++d) {
        int id = sidx[d][rloc];
        if (id < NN) {
            const float* gp = x + (size_t)id * CC + kb;
            #pragma unroll
            for (int kt = 0; kt < 4; ++kt) {
                f32x4 a = *(const f32x4*)(gp + kt * 32);
                f32x4 b = *(const f32x4*)(gp + kt * 32 + 4);
                #pragma unroll
                for (int j = 0; j < 4; ++j) { hacc[kt][j] += a[j]; hacc[kt][4 + j] += b[j]; }
            }
        }
    }
    s16x8 afrag[4];
    #pragma unroll
    for (int kt = 0; kt < 4; ++kt)
        #pragma unroll
        for (int j = 0; j < 8; ++j) afrag[kt][j] = (short)f2b(hacc[kt][j]);
    f32x4 acc[8];
    #pragma unroll
    for (int nt = 0; nt < 8; ++nt) acc[nt] = (f32x4){0.f, 0.f, 0.f, 0.f};
    #pragma unroll
    for (int nt = 0; nt < 8; ++nt) {
        #pragma unroll
        for (int kt = 0; kt < 4; ++kt) {
            s16x8 bfrag;
            const f32x4* p = (const f32x4*)(W + (size_t)(nt * 16 + lr) * CC + kt * 32 + kb);
            f32x4 a = p[0], b = p[1];
            #pragma unroll
            for (int j = 0; j < 4; ++j) { bfrag[j] = (short)f2b(a[j]); bfrag[4 + j] = (short)f2b(b[j]); }
            acc[nt] = __builtin_amdgcn_mfma_f32_16x16x32_bf16(afrag[kt], bfrag, acc[nt], 0, 0, 0);
        }
    }
    #pragma unroll
    for (int nt = 0; nt < 8; ++nt) {
        float bv = bias[nt * 16 + lr];
        #pragma unroll
        for (int j = 0; j < 4; ++j) {
            int orow = base + w * 16 + lk * 4 + j;
            if (orow < NN) out[(size_t)orow * CC + nt * 16 + lr] = acc[nt][j] + bv;
        }
    }
}

extern "C" void kernel_launch(void* const* d_in, const int* in_sizes, int n_in,
                              void* d_out, int out_size, void* d_ws, size_t ws_size,
                              hipStream_t stream) {
    const float* x = (const float*)d_in[0];
    const int* ei = (const int*)d_in[1];
    const float* eps = (const float*)d_in[2];
    const float* W = (const float*)d_in[3];
    const float* b = (const float*)d_in[4];
    float* out = (float*)d_out;

    const size_t xb_elems = (size_t)(NN + 1) * CC;
    const size_t need = (xb_elems + (size_t)CC * CC) * sizeof(unsigned short);
    const int grid = (NN + 63) / 64;

    if (ws_size >= need) {
        unsigned short* xbp = (unsigned short*)d_ws;
        unsigned short* Wbp = xbp + xb_elems;
        cvt_x<<<2048, 256, 0, stream>>>(x, xbp);
        cvt_w<<<16, 256, 0, stream>>>(W, Wbp);
        gin_main<<<grid, 256, 0, stream>>>(xbp, ei, eps, Wbp, b, out);
    } else {
        gin_f32<<<grid, 256, 0, stream>>>(x, ei, eps, W, b, out);
    }
}